// Round 2
// baseline (352.933 us; speedup 1.0000x reference)
//
#include <hip/hip_runtime.h>
#include <hip/hip_bf16.h>
#include <type_traits>

#define B_ 2
#define S_ 2048
#define DM_ 1024
#define H_ 16
#define KH_ 4
#define HD_ 64
#define NREP_ 4

typedef float f32x4 __attribute__((ext_vector_type(4)));
typedef short s16x8 __attribute__((ext_vector_type(8)));

static __device__ __forceinline__ float bf2f(unsigned short u) {
  union { unsigned int u; float f; } x; x.u = ((unsigned int)u) << 16; return x.f;
}
static __device__ __forceinline__ unsigned short f2bf(float f) {
  union { float f; unsigned int u; } x; x.f = f;
  unsigned int r = (x.u + 0x7fffu + ((x.u >> 16) & 1u)) >> 16;
  return (unsigned short)r;
}

__device__ __forceinline__ void gload_lds16(const unsigned short* g, unsigned short* l) {
  __builtin_amdgcn_global_load_lds(
      (const __attribute__((address_space(1))) unsigned int*)g,
      (__attribute__((address_space(3))) unsigned int*)l, 16, 0, 0);
}

// ---------------- f32 -> bf16 conversion (4 elems/thread) -------------------
__global__ void cvt_bf16_k(const float* __restrict__ in, unsigned short* __restrict__ out, int n) {
  int i = (blockIdx.x * 256 + threadIdx.x) * 4;
  if (i >= n) return;
  float4 v = *(const float4*)(in + i);
  ushort4 o;
  o.x = f2bf(v.x); o.y = f2bf(v.y); o.z = f2bf(v.z); o.w = f2bf(v.w);
  *(ushort4*)(out + i) = o;
}

// ---------------- GEMM: C[M,N] = A[M,K] @ Bw[N,K]^T, bf16 in, fp32 accum ----
#define BM 128
#define BN 128
#define BK 32

template <typename OT>
__global__ __launch_bounds__(256) void gemm_bt(const unsigned short* __restrict__ A,
                                               const unsigned short* __restrict__ Bw,
                                               OT* __restrict__ C,
                                               int M, int N, int K) {
  __shared__ unsigned short lds_a[BM * BK];
  __shared__ unsigned short lds_b[BN * BK];
  const int tid = threadIdx.x;
  const int wave = tid >> 6, lane = tid & 63;
  const int lr = lane & 15, lg = lane >> 4;
  const int m0 = blockIdx.y * BM, n0 = blockIdx.x * BN;
  const int wr = wave >> 1, wc = wave & 1;

  f32x4 acc[4][4] = {};

  for (int k0 = 0; k0 < K; k0 += BK) {
    #pragma unroll
    for (int i = 0; i < 2; ++i) {
      int cbase = i * 256 + wave * 64;
      int c = cbase + lane;
      int row = c >> 2, col = (c & 3) << 3;
      gload_lds16(A + (size_t)(m0 + row) * K + k0 + col, &lds_a[cbase * 8]);
      gload_lds16(Bw + (size_t)(n0 + row) * K + k0 + col, &lds_b[cbase * 8]);
    }
    __syncthreads();
    s16x8 af[4], bfr[4];
    #pragma unroll
    for (int mi = 0; mi < 4; ++mi)
      af[mi] = *(const s16x8*)&lds_a[(wr * 64 + mi * 16 + lr) * BK + lg * 8];
    #pragma unroll
    for (int ni = 0; ni < 4; ++ni)
      bfr[ni] = *(const s16x8*)&lds_b[(wc * 64 + ni * 16 + lr) * BK + lg * 8];
    #pragma unroll
    for (int mi = 0; mi < 4; ++mi) {
      #pragma unroll
      for (int ni = 0; ni < 4; ++ni)
        acc[mi][ni] = __builtin_amdgcn_mfma_f32_16x16x32_bf16(af[mi], bfr[ni], acc[mi][ni], 0, 0, 0);
    }
    __syncthreads();
  }
  #pragma unroll
  for (int mi = 0; mi < 4; ++mi) {
    #pragma unroll
    for (int ni = 0; ni < 4; ++ni) {
      #pragma unroll
      for (int r = 0; r < 4; ++r) {
        int row = m0 + wr * 64 + mi * 16 + lg * 4 + r;
        int col = n0 + wc * 64 + ni * 16 + lr;
        if constexpr (std::is_same<OT, unsigned short>::value)
          C[(size_t)row * N + col] = f2bf(acc[mi][ni][r]);
        else
          C[(size_t)row * N + col] = acc[mi][ni][r];
      }
    }
  }
}

// ---------------- RoPE (in place, bf16 buf, f32 freqs) ----------------------
__global__ void rope_k(unsigned short* __restrict__ buf,
                       const float* __restrict__ fc,
                       const float* __restrict__ fs, int heads) {
  int idx = blockIdx.x * 256 + threadIdx.x;
  int i = idx & 31;
  int t2 = idx >> 5;
  int hh = t2 % heads;
  int t3 = t2 / heads;
  int s = t3 & (S_ - 1);
  int bb = t3 >> 11;
  size_t off = ((size_t)(bb * S_ + s) * heads + hh) * HD_ + i * 2;
  float xr = bf2f(buf[off]), xi = bf2f(buf[off + 1]);
  float c = fc[s * 32 + i], sn = fs[s * 32 + i];
  buf[off]     = f2bf(xr * c - xi * sn);
  buf[off + 1] = f2bf(xr * sn + xi * c);
}

// ---------------- V transpose: [b][s][kh*64+d] -> [b][kh][d][S] -------------
__global__ void vtrans_k(const unsigned short* __restrict__ v,
                         unsigned short* __restrict__ vt) {
  int idx = blockIdx.x * 256 + threadIdx.x;
  int s = idx & (S_ - 1);
  int row = idx >> 11;
  int d = row & (HD_ - 1);
  int kh = (row >> 6) & (KH_ - 1);
  int b = row >> 8;
  vt[idx] = v[(size_t)(b * S_ + s) * (KH_ * HD_) + kh * HD_ + d];
}

// ---------------- Flash attention (causal, GQA) -----------------------------
__global__ __launch_bounds__(256) void attn_fwd(const unsigned short* __restrict__ qb,
                                                const unsigned short* __restrict__ kb,
                                                const unsigned short* __restrict__ vt,
                                                unsigned short* __restrict__ ob) {
  __shared__ unsigned short p_lds[4][16 * 32];
  const int tid = threadIdx.x;
  const int wave = tid >> 6, lane = tid & 63;
  const int lr = lane & 15, lg = lane >> 4;
  int bx = blockIdx.x;
  const int nqt = S_ / 64;
  int qt = bx % nqt;
  int h = (bx / nqt) % H_;
  int b = bx / (nqt * H_);
  int kh = h / NREP_;
  int qbase = qt * 64 + wave * 16;

  const unsigned short* qrow = qb + (size_t)(b * S_ + qbase + lr) * DM_ + h * HD_;
  s16x8 qf0 = *(const s16x8*)(qrow + lg * 8);
  s16x8 qf1 = *(const s16x8*)(qrow + 32 + lg * 8);

  const unsigned short* kbp = kb + (size_t)b * S_ * (KH_ * HD_) + kh * HD_;
  const unsigned short* vtp = vt + (size_t)((b * KH_ + kh) * HD_) * S_;

  f32x4 oacc[4] = {};
  float m_r[4], l_r[4];
  #pragma unroll
  for (int r = 0; r < 4; ++r) { m_r[r] = -1e30f; l_r[r] = 0.f; }

  int tmax = (qbase + 15) >> 5;
  for (int t = 0; t <= tmax; ++t) {
    int kv0 = t * 32;
    f32x4 sc[2] = {};
    #pragma unroll
    for (int cf = 0; cf < 2; ++cf) {
      const unsigned short* krow = kbp + (size_t)(kv0 + cf * 16 + lr) * (KH_ * HD_);
      s16x8 kf0 = *(const s16x8*)(krow + lg * 8);
      s16x8 kf1 = *(const s16x8*)(krow + 32 + lg * 8);
      sc[cf] = __builtin_amdgcn_mfma_f32_16x16x32_bf16(qf0, kf0, sc[cf], 0, 0, 0);
      sc[cf] = __builtin_amdgcn_mfma_f32_16x16x32_bf16(qf1, kf1, sc[cf], 0, 0, 0);
    }
    bool need_mask = (kv0 + 31) > qbase;
    float s0[4], s1[4], mx[4];
    #pragma unroll
    for (int r = 0; r < 4; ++r) {
      int q = qbase + lg * 4 + r;
      float a0 = sc[0][r] * 0.125f;
      float a1 = sc[1][r] * 0.125f;
      if (need_mask) {
        if (kv0 + lr > q)      a0 = -1e30f;
        if (kv0 + 16 + lr > q) a1 = -1e30f;
      }
      s0[r] = a0; s1[r] = a1;
      float m = fmaxf(a0, a1);
      m = fmaxf(m, __shfl_xor(m, 1));
      m = fmaxf(m, __shfl_xor(m, 2));
      m = fmaxf(m, __shfl_xor(m, 4));
      m = fmaxf(m, __shfl_xor(m, 8));
      mx[r] = m;
    }
    unsigned short* pw = p_lds[wave];
    #pragma unroll
    for (int r = 0; r < 4; ++r) {
      float mnew = fmaxf(m_r[r], mx[r]);
      float fr = __expf(m_r[r] - mnew);
      m_r[r] = mnew;
      float p0 = __expf(s0[r] - mnew);
      float p1 = __expf(s1[r] - mnew);
      float rs = p0 + p1;
      rs += __shfl_xor(rs, 1);
      rs += __shfl_xor(rs, 2);
      rs += __shfl_xor(rs, 4);
      rs += __shfl_xor(rs, 8);
      l_r[r] = l_r[r] * fr + rs;
      #pragma unroll
      for (int df = 0; df < 4; ++df) oacc[df][r] *= fr;
      pw[(lg * 4 + r) * 32 + lr]      = f2bf(p0);
      pw[(lg * 4 + r) * 32 + 16 + lr] = f2bf(p1);
    }
    asm volatile("s_waitcnt lgkmcnt(0)" ::: "memory");
    __builtin_amdgcn_sched_barrier(0);
    s16x8 pf = *(const s16x8*)&pw[lr * 32 + lg * 8];
    #pragma unroll
    for (int df = 0; df < 4; ++df) {
      s16x8 vf = *(const s16x8*)(vtp + (size_t)(df * 16 + lr) * S_ + kv0 + lg * 8);
      oacc[df] = __builtin_amdgcn_mfma_f32_16x16x32_bf16(pf, vf, oacc[df], 0, 0, 0);
    }
    asm volatile("s_waitcnt lgkmcnt(0)" ::: "memory");
    __builtin_amdgcn_sched_barrier(0);
  }
  #pragma unroll
  for (int df = 0; df < 4; ++df) {
    #pragma unroll
    for (int r = 0; r < 4; ++r) {
      int q = qbase + lg * 4 + r;
      float o = oacc[df][r] / l_r[r];
      ob[(size_t)(b * S_ + q) * DM_ + h * HD_ + df * 16 + lr] = f2bf(o);
    }
  }
}

extern "C" void kernel_launch(void* const* d_in, const int* in_sizes, int n_in,
                              void* d_out, int out_size, void* d_ws, size_t ws_size,
                              hipStream_t stream) {
  const float* x  = (const float*)d_in[0];
  const float* wq = (const float*)d_in[1];
  const float* wk = (const float*)d_in[2];
  const float* wv = (const float*)d_in[3];
  const float* wo = (const float*)d_in[4];
  const float* fc = (const float*)d_in[5];
  const float* fs = (const float*)d_in[6];
  float* out = (float*)d_out;

  const size_t nX  = (size_t)B_ * S_ * DM_;        // 4,194,304
  const size_t nWq = (size_t)H_ * HD_ * DM_;       // 1,048,576
  const size_t nWk = (size_t)KH_ * HD_ * DM_;      //   262,144
  const size_t nKV = (size_t)B_ * S_ * KH_ * HD_;  // 1,048,576

  unsigned short* xb   = (unsigned short*)d_ws;
  unsigned short* wqb  = xb   + nX;
  unsigned short* wkb  = wqb  + nWq;
  unsigned short* wvb  = wkb  + nWk;
  unsigned short* wob  = wvb  + nWk;
  unsigned short* q_buf  = wob  + nWq;
  unsigned short* k_buf  = q_buf  + nX;
  unsigned short* v_buf  = k_buf  + nKV;
  unsigned short* vt_buf = v_buf  + nKV;
  unsigned short* a_buf  = vt_buf + nKV;

  const int M = B_ * S_;
  dim3 blk(256);

  cvt_bf16_k<<<nX  / 1024, blk, 0, stream>>>(x,  xb,  (int)nX);
  cvt_bf16_k<<<nWq / 1024, blk, 0, stream>>>(wq, wqb, (int)nWq);
  cvt_bf16_k<<<nWk / 1024, blk, 0, stream>>>(wk, wkb, (int)nWk);
  cvt_bf16_k<<<nWk / 1024, blk, 0, stream>>>(wv, wvb, (int)nWk);
  cvt_bf16_k<<<nWq / 1024, blk, 0, stream>>>(wo, wob, (int)nWq);

  gemm_bt<unsigned short><<<dim3(DM_ / BN, M / BM), blk, 0, stream>>>(xb, wqb, q_buf, M, DM_, DM_);
  gemm_bt<unsigned short><<<dim3((KH_ * HD_) / BN, M / BM), blk, 0, stream>>>(xb, wkb, k_buf, M, KH_ * HD_, DM_);
  gemm_bt<unsigned short><<<dim3((KH_ * HD_) / BN, M / BM), blk, 0, stream>>>(xb, wvb, v_buf, M, KH_ * HD_, DM_);

  rope_k<<<(B_ * S_ * H_ * 32) / 256, blk, 0, stream>>>(q_buf, fc, fs, H_);
  rope_k<<<(B_ * S_ * KH_ * 32) / 256, blk, 0, stream>>>(k_buf, fc, fs, KH_);
  vtrans_k<<<(B_ * S_ * KH_ * HD_) / 256, blk, 0, stream>>>(v_buf, vt_buf);

  attn_fwd<<<B_ * H_ * (S_ / 64), blk, 0, stream>>>(q_buf, k_buf, vt_buf, a_buf);

  gemm_bt<float><<<dim3(DM_ / BN, M / BM), blk, 0, stream>>>(a_buf, wob, out, M, DM_, DM_);
}

// Round 3
// 216.434 us; speedup vs baseline: 1.6307x; 1.6307x over previous
//
#include <hip/hip_runtime.h>
#include <hip/hip_bf16.h>
#include <type_traits>

#define B_ 2
#define S_ 2048
#define DM_ 1024
#define H_ 16
#define KH_ 4
#define HD_ 64
#define NREP_ 4

typedef float f32x4 __attribute__((ext_vector_type(4)));
typedef float f32x16 __attribute__((ext_vector_type(16)));
typedef short s16x8 __attribute__((ext_vector_type(8)));
typedef unsigned int u32x2 __attribute__((ext_vector_type(2)));

static __device__ __forceinline__ float bf2f(unsigned short u) {
  union { unsigned int u; float f; } x; x.u = ((unsigned int)u) << 16; return x.f;
}
static __device__ __forceinline__ unsigned short f2bf(float f) {
  union { float f; unsigned int u; } x; x.f = f;
  unsigned int r = (x.u + 0x7fffu + ((x.u >> 16) & 1u)) >> 16;
  return (unsigned short)r;
}
static __device__ __forceinline__ unsigned int cvtpk_bf16(float lo, float hi) {
  unsigned int r;
  asm("v_cvt_pk_bf16_f32 %0, %1, %2" : "=v"(r) : "v"(lo), "v"(hi));
  return r;
}

__device__ __forceinline__ void gload_lds16(const unsigned short* g, unsigned short* l) {
  __builtin_amdgcn_global_load_lds(
      (const __attribute__((address_space(1))) unsigned int*)g,
      (__attribute__((address_space(3))) unsigned int*)l, 16, 0, 0);
}

// ---------------- f32 -> bf16 conversion (4 elems/thread) -------------------
__global__ void cvt_bf16_k(const float* __restrict__ in, unsigned short* __restrict__ out, int n) {
  int i = (blockIdx.x * 256 + threadIdx.x) * 4;
  if (i >= n) return;
  float4 v = *(const float4*)(in + i);
  ushort4 o;
  o.x = f2bf(v.x); o.y = f2bf(v.y); o.z = f2bf(v.z); o.w = f2bf(v.w);
  *(ushort4*)(out + i) = o;
}

// ---------------- GEMM: C[M,N] = A[M,K] @ Bw[N,K]^T, bf16 in, fp32 accum ----
#define BM 128
#define BN 128
#define BK 32

template <typename OT>
__global__ __launch_bounds__(256) void gemm_bt(const unsigned short* __restrict__ A,
                                               const unsigned short* __restrict__ Bw,
                                               OT* __restrict__ C,
                                               int M, int N, int K) {
  __shared__ unsigned short lds_a[BM * BK];
  __shared__ unsigned short lds_b[BN * BK];
  const int tid = threadIdx.x;
  const int wave = tid >> 6, lane = tid & 63;
  const int lr = lane & 15, lg = lane >> 4;
  const int m0 = blockIdx.y * BM, n0 = blockIdx.x * BN;
  const int wr = wave >> 1, wc = wave & 1;

  f32x4 acc[4][4] = {};

  for (int k0 = 0; k0 < K; k0 += BK) {
    #pragma unroll
    for (int i = 0; i < 2; ++i) {
      int cbase = i * 256 + wave * 64;
      int c = cbase + lane;
      int row = c >> 2, col = (c & 3) << 3;
      gload_lds16(A + (size_t)(m0 + row) * K + k0 + col, &lds_a[cbase * 8]);
      gload_lds16(Bw + (size_t)(n0 + row) * K + k0 + col, &lds_b[cbase * 8]);
    }
    __syncthreads();
    s16x8 af[4], bfr[4];
    #pragma unroll
    for (int mi = 0; mi < 4; ++mi)
      af[mi] = *(const s16x8*)&lds_a[(wr * 64 + mi * 16 + lr) * BK + lg * 8];
    #pragma unroll
    for (int ni = 0; ni < 4; ++ni)
      bfr[ni] = *(const s16x8*)&lds_b[(wc * 64 + ni * 16 + lr) * BK + lg * 8];
    #pragma unroll
    for (int mi = 0; mi < 4; ++mi) {
      #pragma unroll
      for (int ni = 0; ni < 4; ++ni)
        acc[mi][ni] = __builtin_amdgcn_mfma_f32_16x16x32_bf16(af[mi], bfr[ni], acc[mi][ni], 0, 0, 0);
    }
    __syncthreads();
  }
  #pragma unroll
  for (int mi = 0; mi < 4; ++mi) {
    #pragma unroll
    for (int ni = 0; ni < 4; ++ni) {
      #pragma unroll
      for (int r = 0; r < 4; ++r) {
        int row = m0 + wr * 64 + mi * 16 + lg * 4 + r;
        int col = n0 + wc * 64 + ni * 16 + lr;
        if constexpr (std::is_same<OT, unsigned short>::value)
          C[(size_t)row * N + col] = f2bf(acc[mi][ni][r]);
        else
          C[(size_t)row * N + col] = acc[mi][ni][r];
      }
    }
  }
}

// ---------------- RoPE (in place, bf16 buf, f32 freqs) ----------------------
__global__ void rope_k(unsigned short* __restrict__ buf,
                       const float* __restrict__ fc,
                       const float* __restrict__ fs, int heads) {
  int idx = blockIdx.x * 256 + threadIdx.x;
  int i = idx & 31;
  int t2 = idx >> 5;
  int hh = t2 % heads;
  int t3 = t2 / heads;
  int s = t3 & (S_ - 1);
  int bb = t3 >> 11;
  size_t off = ((size_t)(bb * S_ + s) * heads + hh) * HD_ + i * 2;
  float xr = bf2f(buf[off]), xi = bf2f(buf[off + 1]);
  float c = fc[s * 32 + i], sn = fs[s * 32 + i];
  buf[off]     = f2bf(xr * c - xi * sn);
  buf[off + 1] = f2bf(xr * sn + xi * c);
}

// ---------------- V transpose: [b][s][kh*64+d] -> [b][kh][d][S] -------------
__global__ void vtrans_k(const unsigned short* __restrict__ v,
                         unsigned short* __restrict__ vt) {
  int idx = blockIdx.x * 256 + threadIdx.x;
  int s = idx & (S_ - 1);
  int row = idx >> 11;
  int d = row & (HD_ - 1);
  int kh = (row >> 6) & (KH_ - 1);
  int b = row >> 8;
  vt[idx] = v[(size_t)(b * S_ + s) * (KH_ * HD_) + kh * HD_ + d];
}

// ---------------- Flash attention v2: swapped-operand 32x32, no LDS ---------
// Per wave: 32 q rows. S^T = K·Q^T via mfma(K,Q): lane owns q=lane&31,
// 16 kv values at kv=(r&3)+8*(r>>2)+4*hi. Softmax lane-local + one shfl(32).
// PV swapped: O^T = V^T·P^T; P^T B-frag built via cvt_pk + shfl(32)+cndmask.
__global__ __launch_bounds__(256) void attn_fwd2(const unsigned short* __restrict__ qb,
                                                 const unsigned short* __restrict__ kb,
                                                 const unsigned short* __restrict__ vt,
                                                 unsigned short* __restrict__ ob) {
  const int tid = threadIdx.x;
  const int wave = tid >> 6, lane = tid & 63;
  const int ql = lane & 31;
  const int hi = lane >> 5;
  const int bx = blockIdx.x;
  const int hb = bx & 31;             // B_*H_ = 32
  const int qcr = bx >> 5;
  const int qc = (S_ / 128 - 1) - qcr;  // heavy chunks dispatched first
  const int h = hb & 15, b = hb >> 4;
  const int kh = h / NREP_;
  const int qbase = qc * 128 + wave * 32;
  const int q = qbase + ql;

  // Q fragments (B-operand of swapped QK): Q[q][d = ks*16 + hi*8 + j]
  const unsigned short* qrow = qb + (size_t)(b * S_ + q) * DM_ + h * HD_;
  s16x8 qfrag[4];
  #pragma unroll
  for (int ks = 0; ks < 4; ++ks)
    qfrag[ks] = *(const s16x8*)(qrow + ks * 16 + hi * 8);

  const unsigned short* kbp = kb + (size_t)b * S_ * (KH_ * HD_) + kh * HD_;
  const unsigned short* vtp = vt + (size_t)((b * KH_ + kh) * HD_) * S_;

  f32x16 oT0 = {};  // O^T rows d 0..31  (lane: d=(r&3)+8*(r>>2)+4*hi, col q=ql)
  f32x16 oT1 = {};  // O^T rows d 32..63
  float m_run = -1e30f, l_run = 0.f;

  const int nt = qbase >> 5;  // tiles 0..nt-1 full, tile nt is the diagonal
  for (int t = 0; t <= nt; ++t) {
    const int kv0 = t << 5;
    const bool diag = (t == nt);

    // --- QK^T (swapped): st[r] = S^T[kv=(r&3)+8*(r>>2)+4*hi][q=ql] ---------
    f32x16 st = {};
    {
      const unsigned short* krow = kbp + (size_t)(kv0 + ql) * (KH_ * HD_) + hi * 8;
      s16x8 kf0 = *(const s16x8*)(krow);
      s16x8 kf1 = *(const s16x8*)(krow + 16);
      s16x8 kf2 = *(const s16x8*)(krow + 32);
      s16x8 kf3 = *(const s16x8*)(krow + 48);
      st = __builtin_amdgcn_mfma_f32_32x32x16_bf16(kf0, qfrag[0], st, 0, 0, 0);
      st = __builtin_amdgcn_mfma_f32_32x32x16_bf16(kf1, qfrag[1], st, 0, 0, 0);
      st = __builtin_amdgcn_mfma_f32_32x32x16_bf16(kf2, qfrag[2], st, 0, 0, 0);
      st = __builtin_amdgcn_mfma_f32_32x32x16_bf16(kf3, qfrag[3], st, 0, 0, 0);
    }

    // --- softmax (lane-local in q) -----------------------------------------
    float sc_[16];
    #pragma unroll
    for (int r = 0; r < 16; ++r) {
      float v = st[r] * 0.125f;
      if (diag) {
        int kvr = (r & 3) + 8 * (r >> 2) + 4 * hi;
        if (kvr > ql) v = -1e30f;
      }
      sc_[r] = v;
    }
    float mx01 = fmaxf(sc_[0], sc_[1]),   mx23 = fmaxf(sc_[2], sc_[3]);
    float mx45 = fmaxf(sc_[4], sc_[5]),   mx67 = fmaxf(sc_[6], sc_[7]);
    float mx89 = fmaxf(sc_[8], sc_[9]),   mxab = fmaxf(sc_[10], sc_[11]);
    float mxcd = fmaxf(sc_[12], sc_[13]), mxef = fmaxf(sc_[14], sc_[15]);
    float mxa = fmaxf(fmaxf(mx01, mx23), fmaxf(mx45, mx67));
    float mxb = fmaxf(fmaxf(mx89, mxab), fmaxf(mxcd, mxef));
    float mx = fmaxf(mxa, mxb);
    mx = fmaxf(mx, __shfl_xor(mx, 32));
    float mnew = fmaxf(m_run, mx);
    float fr = __expf(m_run - mnew);
    m_run = mnew;

    float pr[16];
    #pragma unroll
    for (int r = 0; r < 16; ++r) pr[r] = __expf(sc_[r] - mnew);
    float s0 = (pr[0] + pr[1]) + (pr[2] + pr[3]);
    float s1 = (pr[4] + pr[5]) + (pr[6] + pr[7]);
    float s2 = (pr[8] + pr[9]) + (pr[10] + pr[11]);
    float s3 = (pr[12] + pr[13]) + (pr[14] + pr[15]);
    float sum = (s0 + s1) + (s2 + s3);
    sum += __shfl_xor(sum, 32);
    l_run = l_run * fr + sum;

    #pragma unroll
    for (int r = 0; r < 16; ++r) { oT0[r] *= fr; oT1[r] *= fr; }

    // --- P^T pack (T12, shfl-safe variant) + PV (swapped) -------------------
    #pragma unroll
    for (int ksv = 0; ksv < 2; ++ksv) {
      unsigned int a01 = cvtpk_bf16(pr[ksv * 8 + 0], pr[ksv * 8 + 1]);
      unsigned int a23 = cvtpk_bf16(pr[ksv * 8 + 2], pr[ksv * 8 + 3]);
      unsigned int b45 = cvtpk_bf16(pr[ksv * 8 + 4], pr[ksv * 8 + 5]);
      unsigned int b67 = cvtpk_bf16(pr[ksv * 8 + 6], pr[ksv * 8 + 7]);
      unsigned int a01s = __shfl_xor(a01, 32);
      unsigned int a23s = __shfl_xor(a23, 32);
      unsigned int b45s = __shfl_xor(b45, 32);
      unsigned int b67s = __shfl_xor(b67, 32);
      union { s16x8 v; unsigned int w[4]; } pb;
      pb.w[0] = hi ? b45s : a01;
      pb.w[1] = hi ? b67s : a23;
      pb.w[2] = hi ? b45  : a01s;
      pb.w[3] = hi ? b67  : a23s;
      const unsigned short* vr = vtp + (size_t)ql * S_ + kv0 + ksv * 16 + hi * 8;
      s16x8 vf0 = *(const s16x8*)(vr);
      s16x8 vf1 = *(const s16x8*)(vr + (size_t)32 * S_);
      oT0 = __builtin_amdgcn_mfma_f32_32x32x16_bf16(vf0, pb.v, oT0, 0, 0, 0);
      oT1 = __builtin_amdgcn_mfma_f32_32x32x16_bf16(vf1, pb.v, oT1, 0, 0, 0);
    }
  }

  // --- epilogue: O[q][d] = O^T/l, pack 4 bf16 (8B) per store ---------------
  float invl = 1.0f / l_run;
  unsigned short* orow = ob + (size_t)(b * S_ + q) * DM_ + h * HD_;
  #pragma unroll
  for (int dblk = 0; dblk < 2; ++dblk) {
    #pragma unroll
    for (int g = 0; g < 4; ++g) {
      float e0 = (dblk ? oT1[4 * g + 0] : oT0[4 * g + 0]) * invl;
      float e1 = (dblk ? oT1[4 * g + 1] : oT0[4 * g + 1]) * invl;
      float e2 = (dblk ? oT1[4 * g + 2] : oT0[4 * g + 2]) * invl;
      float e3 = (dblk ? oT1[4 * g + 3] : oT0[4 * g + 3]) * invl;
      u32x2 w;
      w.x = cvtpk_bf16(e0, e1);
      w.y = cvtpk_bf16(e2, e3);
      *(u32x2*)(orow + dblk * 32 + g * 8 + 4 * hi) = w;
    }
  }
}

extern "C" void kernel_launch(void* const* d_in, const int* in_sizes, int n_in,
                              void* d_out, int out_size, void* d_ws, size_t ws_size,
                              hipStream_t stream) {
  const float* x  = (const float*)d_in[0];
  const float* wq = (const float*)d_in[1];
  const float* wk = (const float*)d_in[2];
  const float* wv = (const float*)d_in[3];
  const float* wo = (const float*)d_in[4];
  const float* fc = (const float*)d_in[5];
  const float* fs = (const float*)d_in[6];
  float* out = (float*)d_out;

  const size_t nX  = (size_t)B_ * S_ * DM_;
  const size_t nWq = (size_t)H_ * HD_ * DM_;
  const size_t nWk = (size_t)KH_ * HD_ * DM_;
  const size_t nKV = (size_t)B_ * S_ * KH_ * HD_;

  unsigned short* xb   = (unsigned short*)d_ws;
  unsigned short* wqb  = xb   + nX;
  unsigned short* wkb  = wqb  + nWq;
  unsigned short* wvb  = wkb  + nWk;
  unsigned short* wob  = wvb  + nWk;
  unsigned short* q_buf  = wob  + nWq;
  unsigned short* k_buf  = q_buf  + nX;
  unsigned short* v_buf  = k_buf  + nKV;
  unsigned short* vt_buf = v_buf  + nKV;
  unsigned short* a_buf  = vt_buf + nKV;

  const int M = B_ * S_;
  dim3 blk(256);

  cvt_bf16_k<<<nX  / 1024, blk, 0, stream>>>(x,  xb,  (int)nX);
  cvt_bf16_k<<<nWq / 1024, blk, 0, stream>>>(wq, wqb, (int)nWq);
  cvt_bf16_k<<<nWk / 1024, blk, 0, stream>>>(wk, wkb, (int)nWk);
  cvt_bf16_k<<<nWk / 1024, blk, 0, stream>>>(wv, wvb, (int)nWk);
  cvt_bf16_k<<<nWq / 1024, blk, 0, stream>>>(wo, wob, (int)nWq);

  gemm_bt<unsigned short><<<dim3(DM_ / BN, M / BM), blk, 0, stream>>>(xb, wqb, q_buf, M, DM_, DM_);
  gemm_bt<unsigned short><<<dim3((KH_ * HD_) / BN, M / BM), blk, 0, stream>>>(xb, wkb, k_buf, M, KH_ * HD_, DM_);
  gemm_bt<unsigned short><<<dim3((KH_ * HD_) / BN, M / BM), blk, 0, stream>>>(xb, wvb, v_buf, M, KH_ * HD_, DM_);

  rope_k<<<(B_ * S_ * H_ * 32) / 256, blk, 0, stream>>>(q_buf, fc, fs, H_);
  rope_k<<<(B_ * S_ * KH_ * 32) / 256, blk, 0, stream>>>(k_buf, fc, fs, KH_);
  vtrans_k<<<(B_ * S_ * KH_ * HD_) / 256, blk, 0, stream>>>(v_buf, vt_buf);

  attn_fwd2<<<(S_ / 128) * B_ * H_, blk, 0, stream>>>(q_buf, k_buf, vt_buf, a_buf);

  gemm_bt<float><<<dim3(DM_ / BN, M / BM), blk, 0, stream>>>(a_buf, wob, out, M, DM_, DM_);
}

// Round 5
// 169.642 us; speedup vs baseline: 2.0805x; 1.2758x over previous
//
#include <hip/hip_runtime.h>
#include <hip/hip_bf16.h>
#include <type_traits>

#define B_ 2
#define S_ 2048
#define DM_ 1024
#define H_ 16
#define KH_ 4
#define HD_ 64
#define NREP_ 4
#define QKV_LD 1536
#define CLOG 0.1803368801111244f   /* 0.125 * log2(e) */
#define THR2 12.0f

typedef float f32x4 __attribute__((ext_vector_type(4)));
typedef float f32x16 __attribute__((ext_vector_type(16)));
typedef short s16x8 __attribute__((ext_vector_type(8)));
typedef unsigned int u32x2 __attribute__((ext_vector_type(2)));

static __device__ __forceinline__ float bf2f(unsigned short u) {
  union { unsigned int u; float f; } x; x.u = ((unsigned int)u) << 16; return x.f;
}
static __device__ __forceinline__ unsigned short f2bf(float f) {
  union { float f; unsigned int u; } x; x.f = f;
  unsigned int r = (x.u + 0x7fffu + ((x.u >> 16) & 1u)) >> 16;
  return (unsigned short)r;
}
static __device__ __forceinline__ unsigned int cvtpk_bf16(float lo, float hi) {
  unsigned int r;
  asm("v_cvt_pk_bf16_f32 %0, %1, %2" : "=v"(r) : "v"(lo), "v"(hi));
  return r;
}

__device__ __forceinline__ void gload_lds16(const unsigned short* g, unsigned short* l) {
  __builtin_amdgcn_global_load_lds(
      (const __attribute__((address_space(1))) unsigned int*)g,
      (__attribute__((address_space(3))) unsigned int*)l, 16, 0, 0);
}

// ---------------- f32 -> bf16 conversion (x) --------------------------------
__global__ void cvt_bf16_k(const float* __restrict__ in, unsigned short* __restrict__ out, int n) {
  int i = (blockIdx.x * 256 + threadIdx.x) * 4;
  if (i >= n) return;
  float4 v = *(const float4*)(in + i);
  ushort4 o;
  o.x = f2bf(v.x); o.y = f2bf(v.y); o.z = f2bf(v.z); o.w = f2bf(v.w);
  *(ushort4*)(out + i) = o;
}

// ---------------- weights cvt: wq|wk|wv -> wqkv, wo -> wob ------------------
__global__ void cvt_w_k(const float* __restrict__ wq, const float* __restrict__ wk,
                        const float* __restrict__ wv, const float* __restrict__ wo,
                        unsigned short* __restrict__ wqkv, unsigned short* __restrict__ wob) {
  int i = (blockIdx.x * 256 + threadIdx.x) * 4;
  const float* src; unsigned short* dst; int off;
  if (i < 1048576)      { src = wq; dst = wqkv;            off = i; }
  else if (i < 1310720) { src = wk; dst = wqkv + 1048576;  off = i - 1048576; }
  else if (i < 1572864) { src = wv; dst = wqkv + 1310720;  off = i - 1310720; }
  else                  { src = wo; dst = wob;             off = i - 1572864; }
  float4 v = *(const float4*)(src + off);
  ushort4 o;
  o.x = f2bf(v.x); o.y = f2bf(v.y); o.z = f2bf(v.z); o.w = f2bf(v.w);
  *(ushort4*)(dst + off) = o;
}

// ---------------- GEMM: C[M,N] = A[M,K] @ Bw[N,K]^T, bf16 in, fp32 accum ----
#define BM 128
#define BN 128
#define BK 32

template <typename OT>
__global__ __launch_bounds__(256) void gemm_bt(const unsigned short* __restrict__ A,
                                               const unsigned short* __restrict__ Bw,
                                               OT* __restrict__ C,
                                               int M, int N, int K) {
  __shared__ unsigned short lds_a[BM * BK];
  __shared__ unsigned short lds_b[BN * BK];
  const int tid = threadIdx.x;
  const int wave = tid >> 6, lane = tid & 63;
  const int lr = lane & 15, lg = lane >> 4;
  const int m0 = blockIdx.y * BM, n0 = blockIdx.x * BN;
  const int wr = wave >> 1, wc = wave & 1;

  f32x4 acc[4][4] = {};

  for (int k0 = 0; k0 < K; k0 += BK) {
    #pragma unroll
    for (int i = 0; i < 2; ++i) {
      int cbase = i * 256 + wave * 64;
      int c = cbase + lane;
      int row = c >> 2, col = (c & 3) << 3;
      gload_lds16(A + (size_t)(m0 + row) * K + k0 + col, &lds_a[cbase * 8]);
      gload_lds16(Bw + (size_t)(n0 + row) * K + k0 + col, &lds_b[cbase * 8]);
    }
    __syncthreads();
    s16x8 af[4], bfr[4];
    #pragma unroll
    for (int mi = 0; mi < 4; ++mi)
      af[mi] = *(const s16x8*)&lds_a[(wr * 64 + mi * 16 + lr) * BK + lg * 8];
    #pragma unroll
    for (int ni = 0; ni < 4; ++ni)
      bfr[ni] = *(const s16x8*)&lds_b[(wc * 64 + ni * 16 + lr) * BK + lg * 8];
    #pragma unroll
    for (int mi = 0; mi < 4; ++mi) {
      #pragma unroll
      for (int ni = 0; ni < 4; ++ni)
        acc[mi][ni] = __builtin_amdgcn_mfma_f32_16x16x32_bf16(af[mi], bfr[ni], acc[mi][ni], 0, 0, 0);
    }
    __syncthreads();
  }
  #pragma unroll
  for (int mi = 0; mi < 4; ++mi) {
    #pragma unroll
    for (int ni = 0; ni < 4; ++ni) {
      #pragma unroll
      for (int r = 0; r < 4; ++r) {
        int row = m0 + wr * 64 + mi * 16 + lg * 4 + r;
        int col = n0 + wc * 64 + ni * 16 + lr;
        if constexpr (std::is_same<OT, unsigned short>::value)
          C[(size_t)row * N + col] = f2bf(acc[mi][ni][r]);
        else
          C[(size_t)row * N + col] = acc[mi][ni][r];
      }
    }
  }
}

// ---------------- RoPE (in place, strided qkv layout) -----------------------
__global__ void rope2_k(unsigned short* __restrict__ buf,
                        const float* __restrict__ fc,
                        const float* __restrict__ fs, int heads) {
  int idx = blockIdx.x * 256 + threadIdx.x;
  int g = idx & 7;
  int t2 = idx >> 3;
  int hh = t2 % heads;
  int t3 = t2 / heads;
  int s = t3 & (S_ - 1);
  int bb = t3 >> 11;
  size_t off = (size_t)(bb * S_ + s) * QKV_LD + hh * HD_ + g * 8;
  s16x8 v = *(s16x8*)(buf + off);
  float4 c4 = *(const float4*)(fc + s * 32 + g * 4);
  float4 s4 = *(const float4*)(fs + s * 32 + g * 4);
  float cc[4] = {c4.x, c4.y, c4.z, c4.w};
  float ss[4] = {s4.x, s4.y, s4.z, s4.w};
  s16x8 o;
  #pragma unroll
  for (int p = 0; p < 4; ++p) {
    float xr = bf2f((unsigned short)v[2 * p]);
    float xi = bf2f((unsigned short)v[2 * p + 1]);
    o[2 * p]     = (short)f2bf(xr * cc[p] - xi * ss[p]);
    o[2 * p + 1] = (short)f2bf(xr * ss[p] + xi * cc[p]);
  }
  *(s16x8*)(buf + off) = o;
}

// ---------------- V transpose: qkv v-cols -> [b][kh][d][S] ------------------
__global__ void vtrans2_k(const unsigned short* __restrict__ qkv,
                          unsigned short* __restrict__ vt) {
  int idx = blockIdx.x * 256 + threadIdx.x;
  int s = idx & (S_ - 1);
  int row = idx >> 11;
  int d = row & (HD_ - 1);
  int kh = (row >> 6) & (KH_ - 1);
  int b = row >> 8;
  vt[idx] = qkv[(size_t)(b * S_ + s) * QKV_LD + 1280 + kh * HD_ + d];
}

// ---------------- Flash attention v3: swapped 32x32, reg dbuf, XCD-local ----
__global__ __launch_bounds__(256, 2) void attn_fwd3(const unsigned short* __restrict__ qkv,
                                                    const unsigned short* __restrict__ vt,
                                                    unsigned short* __restrict__ ob) {
  const int tid = threadIdx.x;
  const int wave = tid >> 6, lane = tid & 63;
  const int ql = lane & 31;
  const int hi = lane >> 5;
  // XCD-local mapping: 8 XCDs <-> 8 (b,kh) panels; heavy q-chunks first.
  const int i = blockIdx.x;
  const int xcd = i & 7, j = i >> 3;
  const int b = xcd >> 2, kh = xcd & 3;
  const int h = kh * NREP_ + (j & 3);
  const int qc = (S_ / 128 - 1) - (j >> 2);
  const int qbase = qc * 128 + wave * 32;
  const int q = qbase + ql;

  const unsigned short* qrow = qkv + (size_t)(b * S_ + q) * QKV_LD + h * HD_;
  s16x8 qf[4];
  #pragma unroll
  for (int ks = 0; ks < 4; ++ks)
    qf[ks] = *(const s16x8*)(qrow + ks * 16 + hi * 8);

  const unsigned short* kbp = qkv + 1024 + (size_t)b * S_ * QKV_LD + kh * HD_;
  const unsigned short* vtp = vt + (size_t)((b * KH_ + kh) * HD_) * S_;

  f32x16 oT0 = {};
  f32x16 oT1 = {};
  float m2 = -1e30f, l = 0.f;

  s16x8 ka[4], va[4], kb2[4], vb2[4];

#define LOADKV(T, KK, VV) do { \
    const unsigned short* kr_ = kbp + (size_t)(((T) << 5) + ql) * QKV_LD + hi * 8; \
    KK[0] = *(const s16x8*)(kr_);      KK[1] = *(const s16x8*)(kr_ + 16); \
    KK[2] = *(const s16x8*)(kr_ + 32); KK[3] = *(const s16x8*)(kr_ + 48); \
    const unsigned short* vr_ = vtp + (size_t)ql * S_ + ((T) << 5) + hi * 8; \
    VV[0] = *(const s16x8*)(vr_);      VV[1] = *(const s16x8*)(vr_ + 16); \
    VV[2] = *(const s16x8*)(vr_ + (size_t)32 * S_); \
    VV[3] = *(const s16x8*)(vr_ + (size_t)32 * S_ + 16); \
  } while (0)

  auto body = [&](s16x8 (&KK)[4], s16x8 (&VV)[4], bool diag) __attribute__((always_inline)) {
    f32x16 st = {};
    __builtin_amdgcn_s_setprio(1);
    st = __builtin_amdgcn_mfma_f32_32x32x16_bf16(KK[0], qf[0], st, 0, 0, 0);
    st = __builtin_amdgcn_mfma_f32_32x32x16_bf16(KK[1], qf[1], st, 0, 0, 0);
    st = __builtin_amdgcn_mfma_f32_32x32x16_bf16(KK[2], qf[2], st, 0, 0, 0);
    st = __builtin_amdgcn_mfma_f32_32x32x16_bf16(KK[3], qf[3], st, 0, 0, 0);
    __builtin_amdgcn_s_setprio(0);
    if (diag) {
      #pragma unroll
      for (int r = 0; r < 16; ++r)
        if (((r & 3) + 8 * (r >> 2) + 4 * hi) > ql) st[r] = -1e30f;
    }
    float mx = fmaxf(st[0], st[1]);
    #pragma unroll
    for (int r = 2; r < 16; ++r) mx = fmaxf(mx, st[r]);
    mx = fmaxf(mx, __shfl_xor(mx, 32));
    float mxC = mx * CLOG;
    if (__any(mxC > m2 + THR2)) {
      float m2n = fmaxf(m2, mxC);
      float fr = exp2f(m2 - m2n);
      m2 = m2n;
      l *= fr;
      #pragma unroll
      for (int r = 0; r < 16; ++r) { oT0[r] *= fr; oT1[r] *= fr; }
    }
    float pr[16];
    #pragma unroll
    for (int r = 0; r < 16; ++r) pr[r] = exp2f(fmaf(st[r], CLOG, -m2));
    float s0 = (pr[0] + pr[1]) + (pr[2] + pr[3]);
    float s1 = (pr[4] + pr[5]) + (pr[6] + pr[7]);
    float s2 = (pr[8] + pr[9]) + (pr[10] + pr[11]);
    float s3 = (pr[12] + pr[13]) + (pr[14] + pr[15]);
    l += (s0 + s1) + (s2 + s3);
    #pragma unroll
    for (int ksv = 0; ksv < 2; ++ksv) {
      unsigned int a01 = cvtpk_bf16(pr[ksv * 8 + 0], pr[ksv * 8 + 1]);
      unsigned int a23 = cvtpk_bf16(pr[ksv * 8 + 2], pr[ksv * 8 + 3]);
      unsigned int b45 = cvtpk_bf16(pr[ksv * 8 + 4], pr[ksv * 8 + 5]);
      unsigned int b67 = cvtpk_bf16(pr[ksv * 8 + 6], pr[ksv * 8 + 7]);
      asm volatile("v_permlane32_swap_b32 %0, %1" : "+v"(a01), "+v"(b45));
      asm volatile("v_permlane32_swap_b32 %0, %1" : "+v"(a23), "+v"(b67));
      union { s16x8 v; unsigned int w[4]; } pb;
      pb.w[0] = a01; pb.w[1] = a23; pb.w[2] = b45; pb.w[3] = b67;
      __builtin_amdgcn_s_setprio(1);
      oT0 = __builtin_amdgcn_mfma_f32_32x32x16_bf16(VV[ksv], pb.v, oT0, 0, 0, 0);
      oT1 = __builtin_amdgcn_mfma_f32_32x32x16_bf16(VV[2 + ksv], pb.v, oT1, 0, 0, 0);
      __builtin_amdgcn_s_setprio(0);
    }
  };

  const int nt = qbase >> 5;
  LOADKV(0, ka, va);
  int t = 0;
  while (t + 1 <= nt) {
    LOADKV(t + 1, kb2, vb2);
    body(ka, va, false);
    ++t;
    if (t + 1 <= nt) LOADKV(t + 1, ka, va);
    body(kb2, vb2, t == nt);
    ++t;
  }
  if (t <= nt) body(ka, va, true);
#undef LOADKV

  float l_tot = l + __shfl_xor(l, 32);
  float invl = 1.0f / l_tot;
  unsigned short* orow = ob + (size_t)(b * S_ + q) * DM_ + h * HD_;
  #pragma unroll
  for (int dblk = 0; dblk < 2; ++dblk) {
    #pragma unroll
    for (int g = 0; g < 4; ++g) {
      float e0 = (dblk ? oT1[4 * g + 0] : oT0[4 * g + 0]) * invl;
      float e1 = (dblk ? oT1[4 * g + 1] : oT0[4 * g + 1]) * invl;
      float e2 = (dblk ? oT1[4 * g + 2] : oT0[4 * g + 2]) * invl;
      float e3 = (dblk ? oT1[4 * g + 3] : oT0[4 * g + 3]) * invl;
      u32x2 w;
      w.x = cvtpk_bf16(e0, e1);
      w.y = cvtpk_bf16(e2, e3);
      *(u32x2*)(orow + dblk * 32 + g * 8 + 4 * hi) = w;
    }
  }
}

extern "C" void kernel_launch(void* const* d_in, const int* in_sizes, int n_in,
                              void* d_out, int out_size, void* d_ws, size_t ws_size,
                              hipStream_t stream) {
  const float* x  = (const float*)d_in[0];
  const float* wq = (const float*)d_in[1];
  const float* wk = (const float*)d_in[2];
  const float* wv = (const float*)d_in[3];
  const float* wo = (const float*)d_in[4];
  const float* fc = (const float*)d_in[5];
  const float* fs = (const float*)d_in[6];
  float* out = (float*)d_out;

  const size_t nX   = (size_t)B_ * S_ * DM_;        // 4,194,304
  const size_t nWQKV = (size_t)QKV_LD * DM_;        // 1,572,864
  const size_t nWO  = (size_t)DM_ * DM_;            // 1,048,576
  const size_t nQKV = (size_t)B_ * S_ * QKV_LD;     // 6,291,456
  const size_t nKV  = (size_t)B_ * S_ * KH_ * HD_;  // 1,048,576

  unsigned short* xb    = (unsigned short*)d_ws;
  unsigned short* wqkv  = xb + nX;
  unsigned short* wob   = wqkv + nWQKV;
  unsigned short* qkv   = wob + nWO;
  unsigned short* vt    = qkv + nQKV;
  unsigned short* a_buf = vt + nKV;

  const int M = B_ * S_;
  dim3 blk(256);

  cvt_bf16_k<<<nX / 1024, blk, 0, stream>>>(x, xb, (int)nX);
  cvt_w_k<<<2560, blk, 0, stream>>>(wq, wk, wv, wo, wqkv, wob);

  gemm_bt<unsigned short><<<dim3(QKV_LD / BN, M / BM), blk, 0, stream>>>(xb, wqkv, qkv, M, QKV_LD, DM_);

  rope2_k<<<(B_ * S_ * H_ * 8) / 256, blk, 0, stream>>>(qkv, fc, fs, H_);
  rope2_k<<<(B_ * S_ * KH_ * 8) / 256, blk, 0, stream>>>(qkv + 1024, fc, fs, KH_);
  vtrans2_k<<<(int)(nKV / 256), blk, 0, stream>>>(qkv, vt);

  attn_fwd3<<<(S_ / 128) * B_ * H_, blk, 0, stream>>>(qkv, vt, a_buf);

  gemm_bt<float><<<dim3(DM_ / BN, M / BM), blk, 0, stream>>>(a_buf, wob, out, M, DM_, DM_);
}

// Round 6
// 151.411 us; speedup vs baseline: 2.3310x; 1.1204x over previous
//
#include <hip/hip_runtime.h>
#include <hip/hip_bf16.h>
#include <type_traits>

#define B_ 2
#define S_ 2048
#define DM_ 1024
#define H_ 16
#define KH_ 4
#define HD_ 64
#define NREP_ 4
#define QKV_LD 1536
#define CLOG 0.1803368801111244f   /* 0.125 * log2(e) */
#define THR2 12.0f

typedef float f32x4 __attribute__((ext_vector_type(4)));
typedef float f32x16 __attribute__((ext_vector_type(16)));
typedef short s16x8 __attribute__((ext_vector_type(8)));
typedef unsigned int u32x2 __attribute__((ext_vector_type(2)));

static __device__ __forceinline__ float bf2f(unsigned short u) {
  union { unsigned int u; float f; } x; x.u = ((unsigned int)u) << 16; return x.f;
}
static __device__ __forceinline__ unsigned short f2bf(float f) {
  union { float f; unsigned int u; } x; x.f = f;
  unsigned int r = (x.u + 0x7fffu + ((x.u >> 16) & 1u)) >> 16;
  return (unsigned short)r;
}
static __device__ __forceinline__ unsigned int cvtpk_bf16(float lo, float hi) {
  unsigned int r;
  asm("v_cvt_pk_bf16_f32 %0, %1, %2" : "=v"(r) : "v"(lo), "v"(hi));
  return r;
}

__device__ __forceinline__ void gload_lds16(const unsigned short* g, unsigned short* l) {
  __builtin_amdgcn_global_load_lds(
      (const __attribute__((address_space(1))) unsigned int*)g,
      (__attribute__((address_space(3))) unsigned int*)l, 16, 0, 0);
}

// ---------------- f32 -> bf16 conversion (x) --------------------------------
__global__ void cvt_bf16_k(const float* __restrict__ in, unsigned short* __restrict__ out, int n) {
  int i = (blockIdx.x * 256 + threadIdx.x) * 4;
  if (i >= n) return;
  float4 v = *(const float4*)(in + i);
  ushort4 o;
  o.x = f2bf(v.x); o.y = f2bf(v.y); o.z = f2bf(v.z); o.w = f2bf(v.w);
  *(ushort4*)(out + i) = o;
}

// ---------------- weights cvt: wq|wk|wv -> wqkv, wo -> wob ------------------
__global__ void cvt_w_k(const float* __restrict__ wq, const float* __restrict__ wk,
                        const float* __restrict__ wv, const float* __restrict__ wo,
                        unsigned short* __restrict__ wqkv, unsigned short* __restrict__ wob) {
  int i = (blockIdx.x * 256 + threadIdx.x) * 4;
  const float* src; unsigned short* dst; int off;
  if (i < 1048576)      { src = wq; dst = wqkv;            off = i; }
  else if (i < 1310720) { src = wk; dst = wqkv + 1048576;  off = i - 1048576; }
  else if (i < 1572864) { src = wv; dst = wqkv + 1310720;  off = i - 1310720; }
  else                  { src = wo; dst = wob;             off = i - 1572864; }
  float4 v = *(const float4*)(src + off);
  ushort4 o;
  o.x = f2bf(v.x); o.y = f2bf(v.y); o.z = f2bf(v.z); o.w = f2bf(v.w);
  *(ushort4*)(dst + off) = o;
}

// ---------------- GEMM: C[M,N] = A[M,K] @ Bw[N,K]^T, bf16 in, fp32 accum ----
#define BM 128
#define BN 128
#define BK 32

template <typename OT>
__global__ __launch_bounds__(256) void gemm_bt(const unsigned short* __restrict__ A,
                                               const unsigned short* __restrict__ Bw,
                                               OT* __restrict__ C,
                                               int M, int N, int K) {
  __shared__ unsigned short lds_a[BM * BK];
  __shared__ unsigned short lds_b[BN * BK];
  const int tid = threadIdx.x;
  const int wave = tid >> 6, lane = tid & 63;
  const int lr = lane & 15, lg = lane >> 4;
  const int m0 = blockIdx.y * BM, n0 = blockIdx.x * BN;
  const int wr = wave >> 1, wc = wave & 1;

  f32x4 acc[4][4] = {};

  for (int k0 = 0; k0 < K; k0 += BK) {
    #pragma unroll
    for (int i = 0; i < 2; ++i) {
      int cbase = i * 256 + wave * 64;
      int c = cbase + lane;
      int row = c >> 2, col = (c & 3) << 3;
      gload_lds16(A + (size_t)(m0 + row) * K + k0 + col, &lds_a[cbase * 8]);
      gload_lds16(Bw + (size_t)(n0 + row) * K + k0 + col, &lds_b[cbase * 8]);
    }
    __syncthreads();
    s16x8 af[4], bfr[4];
    #pragma unroll
    for (int mi = 0; mi < 4; ++mi)
      af[mi] = *(const s16x8*)&lds_a[(wr * 64 + mi * 16 + lr) * BK + lg * 8];
    #pragma unroll
    for (int ni = 0; ni < 4; ++ni)
      bfr[ni] = *(const s16x8*)&lds_b[(wc * 64 + ni * 16 + lr) * BK + lg * 8];
    #pragma unroll
    for (int mi = 0; mi < 4; ++mi) {
      #pragma unroll
      for (int ni = 0; ni < 4; ++ni)
        acc[mi][ni] = __builtin_amdgcn_mfma_f32_16x16x32_bf16(af[mi], bfr[ni], acc[mi][ni], 0, 0, 0);
    }
    __syncthreads();
  }
  #pragma unroll
  for (int mi = 0; mi < 4; ++mi) {
    #pragma unroll
    for (int ni = 0; ni < 4; ++ni) {
      #pragma unroll
      for (int r = 0; r < 4; ++r) {
        int row = m0 + wr * 64 + mi * 16 + lg * 4 + r;
        int col = n0 + wc * 64 + ni * 16 + lr;
        if constexpr (std::is_same<OT, unsigned short>::value)
          C[(size_t)row * N + col] = f2bf(acc[mi][ni][r]);
        else
          C[(size_t)row * N + col] = acc[mi][ni][r];
      }
    }
  }
}

// ---------------- RoPE (in place, q+k heads in one dispatch) ----------------
__global__ void rope3_k(unsigned short* __restrict__ buf,
                        const float* __restrict__ fc,
                        const float* __restrict__ fs) {
  int idx = blockIdx.x * 256 + threadIdx.x;
  int g = idx & 7;
  int t2 = idx >> 3;
  int slot = t2 % 20;               // 0..15 -> q heads, 16..19 -> k heads
  int t3 = t2 / 20;
  int s = t3 & (S_ - 1);
  int bb = t3 >> 11;
  int col = slot < 16 ? slot * 64 : 1024 + (slot - 16) * 64;
  size_t off = (size_t)(bb * S_ + s) * QKV_LD + col + g * 8;
  s16x8 v = *(s16x8*)(buf + off);
  float4 c4 = *(const float4*)(fc + s * 32 + g * 4);
  float4 s4 = *(const float4*)(fs + s * 32 + g * 4);
  float cc[4] = {c4.x, c4.y, c4.z, c4.w};
  float ss[4] = {s4.x, s4.y, s4.z, s4.w};
  s16x8 o;
  #pragma unroll
  for (int p = 0; p < 4; ++p) {
    float xr = bf2f((unsigned short)v[2 * p]);
    float xi = bf2f((unsigned short)v[2 * p + 1]);
    o[2 * p]     = (short)f2bf(xr * cc[p] - xi * ss[p]);
    o[2 * p + 1] = (short)f2bf(xr * ss[p] + xi * cc[p]);
  }
  *(s16x8*)(buf + off) = o;
}

// ---------------- V transpose: qkv v-cols -> [b][kh][d][S] ------------------
__global__ void vtrans2_k(const unsigned short* __restrict__ qkv,
                          unsigned short* __restrict__ vt) {
  int idx = blockIdx.x * 256 + threadIdx.x;
  int s = idx & (S_ - 1);
  int row = idx >> 11;
  int d = row & (HD_ - 1);
  int kh = (row >> 6) & (KH_ - 1);
  int b = row >> 8;
  vt[idx] = qkv[(size_t)(b * S_ + s) * QKV_LD + 1280 + kh * HD_ + d];
}

// ---------------- Flash attention v4: split-KV balanced, swapped 32x32 ------
// 768 blocks: xcd=bi&7 -> (b,kh) panel; j=bi>>3: h = kh*4+(j&3); bt=j>>2:
//   bt<16 (heavy): waves {0,1} chunk cA=32+bt, waves {2,3} chunk cB=63-bt,
//                  each chunk's KV tiles split in half, merged via LDS.
//   bt>=16 (light): wave w handles chunk c=(bt-16)+8w alone.
__global__ __launch_bounds__(256, 3) void attn_fwd4(const unsigned short* __restrict__ qkv,
                                                    const unsigned short* __restrict__ vt,
                                                    unsigned short* __restrict__ ob) {
  __shared__ float mbuf[2][64][34];
  const int tid = threadIdx.x;
  const int wave = tid >> 6, lane = tid & 63;
  const int ql = lane & 31;
  const int hi = lane >> 5;
  const int bi = blockIdx.x;
  const int xcd = bi & 7;
  const int b = xcd >> 2, kh = xcd & 3;
  const int j = bi >> 3;
  const int h = kh * NREP_ + (j & 3);
  const int bt = j >> 2;
  const bool heavy = bt < 16;
  int c, t0, t1, role, pairIdx = 0;   // role: 0 solo, 1 A(merge owner), 2 B
  if (heavy) {
    pairIdx = wave >> 1;
    c = pairIdx ? (63 - bt) : (32 + bt);
    int T = c + 1, Th = T >> 1;
    if ((wave & 1) == 0) { t0 = 0;  t1 = Th; role = 1; }
    else                 { t0 = Th; t1 = T;  role = 2; }
  } else {
    c = (bt - 16) + 8 * wave;
    t0 = 0; t1 = c + 1; role = 0;
  }
  const int q = c * 32 + ql;

  const unsigned short* qrow = qkv + (size_t)(b * S_ + q) * QKV_LD + h * HD_;
  s16x8 qf[4];
  #pragma unroll
  for (int ks = 0; ks < 4; ++ks)
    qf[ks] = *(const s16x8*)(qrow + ks * 16 + hi * 8);

  const unsigned short* kbp = qkv + 1024 + (size_t)b * S_ * QKV_LD + kh * HD_;
  const unsigned short* vtp = vt + (size_t)((b * KH_ + kh) * HD_) * S_;

  f32x16 oT0 = {};
  f32x16 oT1 = {};
  float m2 = -1e30f, l = 0.f;

  s16x8 ka[4], va[4], kb2[4], vb2[4];

#define LOADKV(T, KK, VV) do { \
    const unsigned short* kr_ = kbp + (size_t)(((T) << 5) + ql) * QKV_LD + hi * 8; \
    KK[0] = *(const s16x8*)(kr_);      KK[1] = *(const s16x8*)(kr_ + 16); \
    KK[2] = *(const s16x8*)(kr_ + 32); KK[3] = *(const s16x8*)(kr_ + 48); \
    const unsigned short* vr_ = vtp + (size_t)ql * S_ + ((T) << 5) + hi * 8; \
    VV[0] = *(const s16x8*)(vr_);      VV[1] = *(const s16x8*)(vr_ + 16); \
    VV[2] = *(const s16x8*)(vr_ + (size_t)32 * S_); \
    VV[3] = *(const s16x8*)(vr_ + (size_t)32 * S_ + 16); \
  } while (0)

  auto body = [&](s16x8 (&KK)[4], s16x8 (&VV)[4], bool diag) __attribute__((always_inline)) {
    f32x16 st = {};
    __builtin_amdgcn_s_setprio(1);
    st = __builtin_amdgcn_mfma_f32_32x32x16_bf16(KK[0], qf[0], st, 0, 0, 0);
    st = __builtin_amdgcn_mfma_f32_32x32x16_bf16(KK[1], qf[1], st, 0, 0, 0);
    st = __builtin_amdgcn_mfma_f32_32x32x16_bf16(KK[2], qf[2], st, 0, 0, 0);
    st = __builtin_amdgcn_mfma_f32_32x32x16_bf16(KK[3], qf[3], st, 0, 0, 0);
    __builtin_amdgcn_s_setprio(0);
    if (diag) {
      #pragma unroll
      for (int r = 0; r < 16; ++r)
        if (((r & 3) + 8 * (r >> 2) + 4 * hi) > ql) st[r] = -1e30f;
    }
    // tree max (v_max3-friendly)
    float m0_ = fmaxf(fmaxf(st[0], st[1]), fmaxf(st[2], st[3]));
    float m1_ = fmaxf(fmaxf(st[4], st[5]), fmaxf(st[6], st[7]));
    float m2_ = fmaxf(fmaxf(st[8], st[9]), fmaxf(st[10], st[11]));
    float m3_ = fmaxf(fmaxf(st[12], st[13]), fmaxf(st[14], st[15]));
    float mx = fmaxf(fmaxf(m0_, m1_), fmaxf(m2_, m3_));
    mx = fmaxf(mx, __shfl_xor(mx, 32));
    float mxC = mx * CLOG;
    if (__any(mxC > m2 + THR2)) {
      float m2n = fmaxf(m2, mxC);
      float fr = exp2f(m2 - m2n);
      m2 = m2n;
      l *= fr;
      #pragma unroll
      for (int r = 0; r < 16; ++r) { oT0[r] *= fr; oT1[r] *= fr; }
    }
    float pr[16];
    #pragma unroll
    for (int r = 0; r < 16; ++r) pr[r] = exp2f(fmaf(st[r], CLOG, -m2));
    float s0 = (pr[0] + pr[1]) + (pr[2] + pr[3]);
    float s1 = (pr[4] + pr[5]) + (pr[6] + pr[7]);
    float s2 = (pr[8] + pr[9]) + (pr[10] + pr[11]);
    float s3 = (pr[12] + pr[13]) + (pr[14] + pr[15]);
    l += (s0 + s1) + (s2 + s3);
    #pragma unroll
    for (int ksv = 0; ksv < 2; ++ksv) {
      unsigned int a01 = cvtpk_bf16(pr[ksv * 8 + 0], pr[ksv * 8 + 1]);
      unsigned int a23 = cvtpk_bf16(pr[ksv * 8 + 2], pr[ksv * 8 + 3]);
      unsigned int b45 = cvtpk_bf16(pr[ksv * 8 + 4], pr[ksv * 8 + 5]);
      unsigned int b67 = cvtpk_bf16(pr[ksv * 8 + 6], pr[ksv * 8 + 7]);
      asm volatile("v_permlane32_swap_b32 %0, %1" : "+v"(a01), "+v"(b45));
      asm volatile("v_permlane32_swap_b32 %0, %1" : "+v"(a23), "+v"(b67));
      union { s16x8 v; unsigned int w[4]; } pb;
      pb.w[0] = a01; pb.w[1] = a23; pb.w[2] = b45; pb.w[3] = b67;
      __builtin_amdgcn_s_setprio(1);
      oT0 = __builtin_amdgcn_mfma_f32_32x32x16_bf16(VV[ksv], pb.v, oT0, 0, 0, 0);
      oT1 = __builtin_amdgcn_mfma_f32_32x32x16_bf16(VV[2 + ksv], pb.v, oT1, 0, 0, 0);
      __builtin_amdgcn_s_setprio(0);
    }
  };

  LOADKV(t0, ka, va);
  int t = t0;
  while (t + 1 < t1) {
    LOADKV(t + 1, kb2, vb2);
    body(ka, va, t == c);
    ++t;
    if (t + 1 < t1) LOADKV(t + 1, ka, va);
    body(kb2, vb2, t == c);
    ++t;
  }
  if (t < t1) body(ka, va, t == c);
#undef LOADKV

  if (heavy) {
    float* mp = &mbuf[pairIdx][lane][0];
    __syncthreads();
    if (role == 2) {
      #pragma unroll
      for (int r = 0; r < 16; ++r) { mp[r] = oT0[r]; mp[16 + r] = oT1[r]; }
      mp[32] = m2; mp[33] = l;
    }
    __syncthreads();
    if (role == 2) return;
    float mB = mp[32], lB = mp[33];
    float mN = fmaxf(m2, mB);
    float fA = exp2f(m2 - mN), fB = exp2f(mB - mN);
    l = l * fA + lB * fB;
    #pragma unroll
    for (int r = 0; r < 16; ++r) {
      oT0[r] = oT0[r] * fA + mp[r] * fB;
      oT1[r] = oT1[r] * fA + mp[16 + r] * fB;
    }
  }

  float l_tot = l + __shfl_xor(l, 32);
  float invl = 1.0f / l_tot;
  unsigned short* orow = ob + (size_t)(b * S_ + q) * DM_ + h * HD_;
  #pragma unroll
  for (int dblk = 0; dblk < 2; ++dblk) {
    #pragma unroll
    for (int g = 0; g < 4; ++g) {
      float e0 = (dblk ? oT1[4 * g + 0] : oT0[4 * g + 0]) * invl;
      float e1 = (dblk ? oT1[4 * g + 1] : oT0[4 * g + 1]) * invl;
      float e2 = (dblk ? oT1[4 * g + 2] : oT0[4 * g + 2]) * invl;
      float e3 = (dblk ? oT1[4 * g + 3] : oT0[4 * g + 3]) * invl;
      u32x2 w;
      w.x = cvtpk_bf16(e0, e1);
      w.y = cvtpk_bf16(e2, e3);
      *(u32x2*)(orow + dblk * 32 + g * 8 + 4 * hi) = w;
    }
  }
}

extern "C" void kernel_launch(void* const* d_in, const int* in_sizes, int n_in,
                              void* d_out, int out_size, void* d_ws, size_t ws_size,
                              hipStream_t stream) {
  const float* x  = (const float*)d_in[0];
  const float* wq = (const float*)d_in[1];
  const float* wk = (const float*)d_in[2];
  const float* wv = (const float*)d_in[3];
  const float* wo = (const float*)d_in[4];
  const float* fc = (const float*)d_in[5];
  const float* fs = (const float*)d_in[6];
  float* out = (float*)d_out;

  const size_t nX    = (size_t)B_ * S_ * DM_;
  const size_t nWQKV = (size_t)QKV_LD * DM_;
  const size_t nWO   = (size_t)DM_ * DM_;
  const size_t nQKV  = (size_t)B_ * S_ * QKV_LD;
  const size_t nKV   = (size_t)B_ * S_ * KH_ * HD_;

  unsigned short* xb    = (unsigned short*)d_ws;
  unsigned short* wqkv  = xb + nX;
  unsigned short* wob   = wqkv + nWQKV;
  unsigned short* qkv   = wob + nWO;
  unsigned short* vt    = qkv + nQKV;
  unsigned short* a_buf = vt + nKV;

  const int M = B_ * S_;
  dim3 blk(256);

  cvt_bf16_k<<<nX / 1024, blk, 0, stream>>>(x, xb, (int)nX);
  cvt_w_k<<<2560, blk, 0, stream>>>(wq, wk, wv, wo, wqkv, wob);

  gemm_bt<unsigned short><<<dim3(QKV_LD / BN, M / BM), blk, 0, stream>>>(xb, wqkv, qkv, M, QKV_LD, DM_);

  rope3_k<<<(B_ * S_ * 20 * 8) / 256, blk, 0, stream>>>(qkv, fc, fs);
  vtrans2_k<<<(int)(nKV / 256), blk, 0, stream>>>(qkv, vt);

  attn_fwd4<<<768, blk, 0, stream>>>(qkv, vt, a_buf);

  gemm_bt<float><<<dim3(DM_ / BN, M / BM), blk, 0, stream>>>(a_buf, wob, out, M, DM_, DM_);
}

// Round 7
// 118.686 us; speedup vs baseline: 2.9737x; 1.2757x over previous
//
#include <hip/hip_runtime.h>
#include <hip/hip_bf16.h>
#include <type_traits>

#define B_ 2
#define S_ 2048
#define DM_ 1024
#define H_ 16
#define KH_ 4
#define HD_ 64
#define NREP_ 4
#define QKV_LD 1536
#define CLOG 0.1803368801111244f   /* 0.125 * log2(e) */
#define THR2 12.0f

typedef float f32x4 __attribute__((ext_vector_type(4)));
typedef float f32x16 __attribute__((ext_vector_type(16)));
typedef short s16x8 __attribute__((ext_vector_type(8)));
typedef unsigned int u32x2 __attribute__((ext_vector_type(2)));

static __device__ __forceinline__ float bf2f(unsigned short u) {
  union { unsigned int u; float f; } x; x.u = ((unsigned int)u) << 16; return x.f;
}
static __device__ __forceinline__ unsigned short f2bf(float f) {
  union { float f; unsigned int u; } x; x.f = f;
  unsigned int r = (x.u + 0x7fffu + ((x.u >> 16) & 1u)) >> 16;
  return (unsigned short)r;
}
static __device__ __forceinline__ unsigned int cvtpk_bf16(float lo, float hi) {
  unsigned int r;
  asm("v_cvt_pk_bf16_f32 %0, %1, %2" : "=v"(r) : "v"(lo), "v"(hi));
  return r;
}

__device__ __forceinline__ void gload_lds16(const unsigned short* g, unsigned short* l) {
  __builtin_amdgcn_global_load_lds(
      (const __attribute__((address_space(1))) unsigned int*)g,
      (__attribute__((address_space(3))) unsigned int*)l, 16, 0, 0);
}

// ---------------- f32 -> bf16 conversion (x) --------------------------------
__global__ void cvt_bf16_k(const float* __restrict__ in, unsigned short* __restrict__ out, int n) {
  int i = (blockIdx.x * 256 + threadIdx.x) * 4;
  if (i >= n) return;
  float4 v = *(const float4*)(in + i);
  ushort4 o;
  o.x = f2bf(v.x); o.y = f2bf(v.y); o.z = f2bf(v.z); o.w = f2bf(v.w);
  *(ushort4*)(out + i) = o;
}

// ---------------- weights cvt: wq|wk|wv -> wqkv, wo -> wob ------------------
__global__ void cvt_w_k(const float* __restrict__ wq, const float* __restrict__ wk,
                        const float* __restrict__ wv, const float* __restrict__ wo,
                        unsigned short* __restrict__ wqkv, unsigned short* __restrict__ wob) {
  int i = (blockIdx.x * 256 + threadIdx.x) * 4;
  const float* src; unsigned short* dst; int off;
  if (i < 1048576)      { src = wq; dst = wqkv;            off = i; }
  else if (i < 1310720) { src = wk; dst = wqkv + 1048576;  off = i - 1048576; }
  else if (i < 1572864) { src = wv; dst = wqkv + 1310720;  off = i - 1310720; }
  else                  { src = wo; dst = wob;             off = i - 1572864; }
  float4 v = *(const float4*)(src + off);
  ushort4 o;
  o.x = f2bf(v.x); o.y = f2bf(v.y); o.z = f2bf(v.z); o.w = f2bf(v.w);
  *(ushort4*)(dst + off) = o;
}

// ---------------- GEMM: C[M,N] = A[M,K] @ Bw[N,K]^T, bf16 in, fp32 accum ----
#define BM 128
#define BN 128
#define BK 32

template <typename OT>
__global__ __launch_bounds__(256) void gemm_bt(const unsigned short* __restrict__ A,
                                               const unsigned short* __restrict__ Bw,
                                               OT* __restrict__ C,
                                               int M, int N, int K) {
  __shared__ unsigned short lds_a[BM * BK];
  __shared__ unsigned short lds_b[BN * BK];
  const int tid = threadIdx.x;
  const int wave = tid >> 6, lane = tid & 63;
  const int lr = lane & 15, lg = lane >> 4;
  const int m0 = blockIdx.y * BM, n0 = blockIdx.x * BN;
  const int wr = wave >> 1, wc = wave & 1;

  f32x4 acc[4][4] = {};

  for (int k0 = 0; k0 < K; k0 += BK) {
    #pragma unroll
    for (int i = 0; i < 2; ++i) {
      int cbase = i * 256 + wave * 64;
      int c = cbase + lane;
      int row = c >> 2, col = (c & 3) << 3;
      gload_lds16(A + (size_t)(m0 + row) * K + k0 + col, &lds_a[cbase * 8]);
      gload_lds16(Bw + (size_t)(n0 + row) * K + k0 + col, &lds_b[cbase * 8]);
    }
    __syncthreads();
    s16x8 af[4], bfr[4];
    #pragma unroll
    for (int mi = 0; mi < 4; ++mi)
      af[mi] = *(const s16x8*)&lds_a[(wr * 64 + mi * 16 + lr) * BK + lg * 8];
    #pragma unroll
    for (int ni = 0; ni < 4; ++ni)
      bfr[ni] = *(const s16x8*)&lds_b[(wc * 64 + ni * 16 + lr) * BK + lg * 8];
    #pragma unroll
    for (int mi = 0; mi < 4; ++mi) {
      #pragma unroll
      for (int ni = 0; ni < 4; ++ni)
        acc[mi][ni] = __builtin_amdgcn_mfma_f32_16x16x32_bf16(af[mi], bfr[ni], acc[mi][ni], 0, 0, 0);
    }
    __syncthreads();
  }
  #pragma unroll
  for (int mi = 0; mi < 4; ++mi) {
    #pragma unroll
    for (int ni = 0; ni < 4; ++ni) {
      #pragma unroll
      for (int r = 0; r < 4; ++r) {
        int row = m0 + wr * 64 + mi * 16 + lg * 4 + r;
        int col = n0 + wc * 64 + ni * 16 + lr;
        if constexpr (std::is_same<OT, unsigned short>::value)
          C[(size_t)row * N + col] = f2bf(acc[mi][ni][r]);
        else
          C[(size_t)row * N + col] = acc[mi][ni][r];
      }
    }
  }
}

// ---------------- RoPE on Q heads only (in place) ---------------------------
__global__ void rope_q_k(unsigned short* __restrict__ buf,
                         const float* __restrict__ fc,
                         const float* __restrict__ fs) {
  int idx = blockIdx.x * 256 + threadIdx.x;
  int g = idx & 7;
  int t2 = idx >> 3;
  int h = t2 & 15;
  int t3 = t2 >> 4;
  int s = t3 & (S_ - 1);
  int bb = t3 >> 11;
  size_t off = (size_t)(bb * S_ + s) * QKV_LD + h * HD_ + g * 8;
  s16x8 v = *(s16x8*)(buf + off);
  float4 c4 = *(const float4*)(fc + s * 32 + g * 4);
  float4 s4 = *(const float4*)(fs + s * 32 + g * 4);
  float cc[4] = {c4.x, c4.y, c4.z, c4.w};
  float ss[4] = {s4.x, s4.y, s4.z, s4.w};
  s16x8 o;
  #pragma unroll
  for (int e = 0; e < 4; ++e) {
    float xr = bf2f((unsigned short)v[2 * e]);
    float xi = bf2f((unsigned short)v[2 * e + 1]);
    o[2 * e]     = (short)f2bf(xr * cc[e] - xi * ss[e]);
    o[2 * e + 1] = (short)f2bf(xr * ss[e] + xi * cc[e]);
  }
  *(s16x8*)(buf + off) = o;
}

// ---------------- K pack (+rope): qkv K cols -> [p][t][ks][lane][8] ---------
__global__ void kpack_k(const unsigned short* __restrict__ qkv,
                        const float* __restrict__ fc, const float* __restrict__ fs,
                        unsigned short* __restrict__ kp) {
  int idx = blockIdx.x * 256 + threadIdx.x;   // ((p*64+t)*4+ks)*64+lane
  int lane = idx & 63;
  int ks = (idx >> 6) & 3;
  int t  = (idx >> 8) & 63;
  int p  = idx >> 14;
  int b = p >> 2, kh = p & 3;
  int ql = lane & 31, hi = lane >> 5;
  int s = t * 32 + ql;
  int d0 = ks * 16 + hi * 8;
  const unsigned short* src = qkv + (size_t)(b * S_ + s) * QKV_LD + 1024 + kh * HD_ + d0;
  s16x8 v = *(const s16x8*)src;
  int i0 = d0 >> 1;
  float4 c4 = *(const float4*)(fc + s * 32 + i0);
  float4 s4 = *(const float4*)(fs + s * 32 + i0);
  float cc[4] = {c4.x, c4.y, c4.z, c4.w};
  float ss[4] = {s4.x, s4.y, s4.z, s4.w};
  s16x8 o;
  #pragma unroll
  for (int e = 0; e < 4; ++e) {
    float xr = bf2f((unsigned short)v[2 * e]);
    float xi = bf2f((unsigned short)v[2 * e + 1]);
    o[2 * e]     = (short)f2bf(xr * cc[e] - xi * ss[e]);
    o[2 * e + 1] = (short)f2bf(xr * ss[e] + xi * cc[e]);
  }
  *(s16x8*)(kp + (size_t)idx * 8) = o;
}

// ---------------- V pack: qkv V cols -> [p][t][j][lane][8] (V^T frags) ------
__global__ void vpack_k(const unsigned short* __restrict__ qkv,
                        unsigned short* __restrict__ vp) {
  int idx = blockIdx.x * 256 + threadIdx.x;
  int lane = idx & 63;
  int j  = (idx >> 6) & 3;
  int t  = (idx >> 8) & 63;
  int p  = idx >> 14;
  int b = p >> 2, kh = p & 3;
  int ql = lane & 31, hi = lane >> 5;
  int d = (j >> 1) * 32 + ql;
  int kv0 = t * 32 + (j & 1) * 16 + hi * 8;
  const unsigned short* src = qkv + (size_t)(b * S_ + kv0) * QKV_LD + 1280 + kh * HD_ + d;
  s16x8 o;
  #pragma unroll
  for (int e = 0; e < 8; ++e) o[e] = (short)src[(size_t)e * QKV_LD];
  *(s16x8*)(vp + (size_t)idx * 8) = o;
}

// ---------------- Flash attention v5: packed K/V, split-KV, swapped 32x32 ---
__global__ __launch_bounds__(256, 3) void attn_fwd5(const unsigned short* __restrict__ qkv,
                                                    const unsigned short* __restrict__ kp,
                                                    const unsigned short* __restrict__ vp,
                                                    unsigned short* __restrict__ ob) {
  __shared__ float mbuf[2][64][34];
  const int tid = threadIdx.x;
  const int wave = tid >> 6, lane = tid & 63;
  const int ql = lane & 31;
  const int hi = lane >> 5;
  const int bi = blockIdx.x;
  const int xcd = bi & 7;
  const int b = xcd >> 2, kh = xcd & 3;
  const int j = bi >> 3;
  const int h = kh * NREP_ + (j & 3);
  const int bt = j >> 2;
  const bool heavy = bt < 16;
  int c, t0, t1, role, pairIdx = 0;   // role: 0 solo, 1 A(merge owner), 2 B
  if (heavy) {
    pairIdx = wave >> 1;
    c = pairIdx ? (63 - bt) : (32 + bt);
    int T = c + 1, Th = T >> 1;
    if ((wave & 1) == 0) { t0 = 0;  t1 = Th; role = 1; }
    else                 { t0 = Th; t1 = T;  role = 2; }
  } else {
    c = (bt - 16) + 8 * wave;
    t0 = 0; t1 = c + 1; role = 0;
  }
  const int q = c * 32 + ql;

  const unsigned short* qrow = qkv + (size_t)(b * S_ + q) * QKV_LD + h * HD_;
  s16x8 qf[4];
  #pragma unroll
  for (int ks = 0; ks < 4; ++ks)
    qf[ks] = *(const s16x8*)(qrow + ks * 16 + hi * 8);

  const unsigned short* kpt = kp + ((size_t)(b * KH_ + kh) << 17) + lane * 8;
  const unsigned short* vpt = vp + ((size_t)(b * KH_ + kh) << 17) + lane * 8;

  f32x16 oT0 = {};
  f32x16 oT1 = {};
  float m2 = -1e30f, l = 0.f;

  s16x8 ka[4], va[4], kb2[4], vb2[4];

#define LOADKV(T, KK, VV) do { \
    const unsigned short* kp_ = kpt + ((size_t)(T) << 11); \
    KK[0] = *(const s16x8*)(kp_);        KK[1] = *(const s16x8*)(kp_ + 512); \
    KK[2] = *(const s16x8*)(kp_ + 1024); KK[3] = *(const s16x8*)(kp_ + 1536); \
    const unsigned short* vp_ = vpt + ((size_t)(T) << 11); \
    VV[0] = *(const s16x8*)(vp_);        VV[1] = *(const s16x8*)(vp_ + 512); \
    VV[2] = *(const s16x8*)(vp_ + 1024); VV[3] = *(const s16x8*)(vp_ + 1536); \
  } while (0)

  auto body = [&](s16x8 (&KK)[4], s16x8 (&VV)[4], bool diag) __attribute__((always_inline)) {
    f32x16 st = {};
    __builtin_amdgcn_s_setprio(1);
    st = __builtin_amdgcn_mfma_f32_32x32x16_bf16(KK[0], qf[0], st, 0, 0, 0);
    st = __builtin_amdgcn_mfma_f32_32x32x16_bf16(KK[1], qf[1], st, 0, 0, 0);
    st = __builtin_amdgcn_mfma_f32_32x32x16_bf16(KK[2], qf[2], st, 0, 0, 0);
    st = __builtin_amdgcn_mfma_f32_32x32x16_bf16(KK[3], qf[3], st, 0, 0, 0);
    __builtin_amdgcn_s_setprio(0);
    if (diag) {
      #pragma unroll
      for (int r = 0; r < 16; ++r)
        if (((r & 3) + 8 * (r >> 2) + 4 * hi) > ql) st[r] = -1e30f;
    }
    float t0_ = fmaxf(fmaxf(st[0], st[1]), fmaxf(st[2], st[3]));
    float t1_ = fmaxf(fmaxf(st[4], st[5]), fmaxf(st[6], st[7]));
    float t2_ = fmaxf(fmaxf(st[8], st[9]), fmaxf(st[10], st[11]));
    float t3_ = fmaxf(fmaxf(st[12], st[13]), fmaxf(st[14], st[15]));
    float mx = fmaxf(fmaxf(t0_, t1_), fmaxf(t2_, t3_));
    mx = fmaxf(mx, __shfl_xor(mx, 32));
    float mxC = mx * CLOG;
    if (__any(mxC > m2 + THR2)) {
      float m2n = fmaxf(m2, mxC);
      float fr = exp2f(m2 - m2n);
      m2 = m2n;
      l *= fr;
      #pragma unroll
      for (int r = 0; r < 16; ++r) { oT0[r] *= fr; oT1[r] *= fr; }
    }
    float pr[16];
    #pragma unroll
    for (int r = 0; r < 16; ++r) pr[r] = exp2f(fmaf(st[r], CLOG, -m2));
    float s0 = (pr[0] + pr[1]) + (pr[2] + pr[3]);
    float s1 = (pr[4] + pr[5]) + (pr[6] + pr[7]);
    float s2 = (pr[8] + pr[9]) + (pr[10] + pr[11]);
    float s3 = (pr[12] + pr[13]) + (pr[14] + pr[15]);
    l += (s0 + s1) + (s2 + s3);
    #pragma unroll
    for (int ksv = 0; ksv < 2; ++ksv) {
      unsigned int a01 = cvtpk_bf16(pr[ksv * 8 + 0], pr[ksv * 8 + 1]);
      unsigned int a23 = cvtpk_bf16(pr[ksv * 8 + 2], pr[ksv * 8 + 3]);
      unsigned int b45 = cvtpk_bf16(pr[ksv * 8 + 4], pr[ksv * 8 + 5]);
      unsigned int b67 = cvtpk_bf16(pr[ksv * 8 + 6], pr[ksv * 8 + 7]);
      asm volatile("v_permlane32_swap_b32 %0, %1" : "+v"(a01), "+v"(b45));
      asm volatile("v_permlane32_swap_b32 %0, %1" : "+v"(a23), "+v"(b67));
      union { s16x8 v; unsigned int w[4]; } pb;
      pb.w[0] = a01; pb.w[1] = a23; pb.w[2] = b45; pb.w[3] = b67;
      __builtin_amdgcn_s_setprio(1);
      oT0 = __builtin_amdgcn_mfma_f32_32x32x16_bf16(VV[ksv], pb.v, oT0, 0, 0, 0);
      oT1 = __builtin_amdgcn_mfma_f32_32x32x16_bf16(VV[2 + ksv], pb.v, oT1, 0, 0, 0);
      __builtin_amdgcn_s_setprio(0);
    }
  };

  LOADKV(t0, ka, va);
  int t = t0;
  while (t + 1 < t1) {
    LOADKV(t + 1, kb2, vb2);
    body(ka, va, t == c);
    ++t;
    if (t + 1 < t1) LOADKV(t + 1, ka, va);
    body(kb2, vb2, t == c);
    ++t;
  }
  if (t < t1) body(ka, va, t == c);
#undef LOADKV

  if (heavy) {
    float* mp = &mbuf[pairIdx][lane][0];
    __syncthreads();
    if (role == 2) {
      #pragma unroll
      for (int r = 0; r < 16; ++r) { mp[r] = oT0[r]; mp[16 + r] = oT1[r]; }
      mp[32] = m2; mp[33] = l;
    }
    __syncthreads();
    if (role == 2) return;
    float mB = mp[32], lB = mp[33];
    float mN = fmaxf(m2, mB);
    float fA = exp2f(m2 - mN), fB = exp2f(mB - mN);
    l = l * fA + lB * fB;
    #pragma unroll
    for (int r = 0; r < 16; ++r) {
      oT0[r] = oT0[r] * fA + mp[r] * fB;
      oT1[r] = oT1[r] * fA + mp[16 + r] * fB;
    }
  }

  float l_tot = l + __shfl_xor(l, 32);
  float invl = 1.0f / l_tot;
  unsigned short* orow = ob + (size_t)(b * S_ + q) * DM_ + h * HD_;
  #pragma unroll
  for (int dblk = 0; dblk < 2; ++dblk) {
    #pragma unroll
    for (int g = 0; g < 4; ++g) {
      float e0 = (dblk ? oT1[4 * g + 0] : oT0[4 * g + 0]) * invl;
      float e1 = (dblk ? oT1[4 * g + 1] : oT0[4 * g + 1]) * invl;
      float e2 = (dblk ? oT1[4 * g + 2] : oT0[4 * g + 2]) * invl;
      float e3 = (dblk ? oT1[4 * g + 3] : oT0[4 * g + 3]) * invl;
      u32x2 w;
      w.x = cvtpk_bf16(e0, e1);
      w.y = cvtpk_bf16(e2, e3);
      *(u32x2*)(orow + dblk * 32 + g * 8 + 4 * hi) = w;
    }
  }
}

extern "C" void kernel_launch(void* const* d_in, const int* in_sizes, int n_in,
                              void* d_out, int out_size, void* d_ws, size_t ws_size,
                              hipStream_t stream) {
  const float* x  = (const float*)d_in[0];
  const float* wq = (const float*)d_in[1];
  const float* wk = (const float*)d_in[2];
  const float* wv = (const float*)d_in[3];
  const float* wo = (const float*)d_in[4];
  const float* fc = (const float*)d_in[5];
  const float* fs = (const float*)d_in[6];
  float* out = (float*)d_out;

  const size_t nX    = (size_t)B_ * S_ * DM_;
  const size_t nWQKV = (size_t)QKV_LD * DM_;
  const size_t nWO   = (size_t)DM_ * DM_;
  const size_t nQKV  = (size_t)B_ * S_ * QKV_LD;
  const size_t nKV   = (size_t)B_ * S_ * KH_ * HD_;   // 1,048,576

  unsigned short* xb    = (unsigned short*)d_ws;
  unsigned short* wqkv  = xb + nX;
  unsigned short* wob   = wqkv + nWQKV;
  unsigned short* qkv   = wob + nWO;
  unsigned short* kpk   = qkv + nQKV;
  unsigned short* vpk   = kpk + nKV;
  unsigned short* a_buf = vpk + nKV;

  const int M = B_ * S_;
  dim3 blk(256);

  cvt_bf16_k<<<nX / 1024, blk, 0, stream>>>(x, xb, (int)nX);
  cvt_w_k<<<2560, blk, 0, stream>>>(wq, wk, wv, wo, wqkv, wob);

  gemm_bt<unsigned short><<<dim3(QKV_LD / BN, M / BM), blk, 0, stream>>>(xb, wqkv, qkv, M, QKV_LD, DM_);

  rope_q_k<<<(B_ * S_ * H_ * 8) / 256, blk, 0, stream>>>(qkv, fc, fs);
  kpack_k<<<512, blk, 0, stream>>>(qkv, fc, fs, kpk);
  vpack_k<<<512, blk, 0, stream>>>(qkv, vpk);

  attn_fwd5<<<768, blk, 0, stream>>>(qkv, kpk, vpk, a_buf);

  gemm_bt<float><<<dim3(DM_ / BN, M / BM), blk, 0, stream>>>(a_buf, wob, out, M, DM_, DM_);
}